// Round 4
// baseline (418.873 us; speedup 1.0000x reference)
//
#include <hip/hip_runtime.h>
#include <stdint.h>

#define N_NODES 100000
#define N_EDGES 600000
#define DIM_H   128
#define DIM_OUT 64
#define WPAD    136      // padded LDS row stride in ushort units
#define BN_EPS  1e-5f
#define NBLK    391      // ceil(N_NODES/256)

typedef __attribute__((ext_vector_type(8))) __bf16        bh8;
typedef __attribute__((ext_vector_type(2))) float         fl2;
typedef __attribute__((ext_vector_type(4))) float         fl4;
typedef __attribute__((ext_vector_type(8))) unsigned short us8;

__device__ __forceinline__ unsigned short f2bfbits(float f) {
  unsigned int u = __builtin_bit_cast(unsigned int, f);
  u += 0x7fffu + ((u >> 16) & 1u);           // RNE
  return (unsigned short)(u >> 16);
}
__device__ __forceinline__ float bf2f(unsigned short b) {
  unsigned int u = ((unsigned int)b) << 16;
  return __builtin_bit_cast(float, u);
}
// in-wave LDS producer->consumer fence (lanes of the same wave only)
__device__ __forceinline__ void wave_lds_fence() {
  asm volatile("s_waitcnt lgkmcnt(0)" ::: "memory");
  __builtin_amdgcn_sched_barrier(0);
}

// ---------------- weight prep + zero stats + zero deg ----------------
__global__ void prep_kernel(const float* __restrict__ cw1, const float* __restrict__ cw2,
                            const float* __restrict__ fc1w, const float* __restrict__ fc2w,
                            unsigned short* __restrict__ W1T, unsigned short* __restrict__ W2T,
                            unsigned short* __restrict__ F1T, unsigned short* __restrict__ F2T,
                            float* __restrict__ stats, int* __restrict__ deg) {
  int t = blockIdx.x * 256 + threadIdx.x;
  if (t < 3 * 16384) {
    int l = t / 16384, r = t % 16384;
    int nn = r >> 7, k = r & 127;            // W*T[l][n][k] = W[l][k][n]
    W1T[t] = f2bfbits(cw1[l * 16384 + k * 128 + nn]);
    W2T[t] = f2bfbits(cw2[l * 16384 + k * 128 + nn]);
  }
  if (t < 16384) { int nn = t >> 7, k = t & 127; F1T[t] = f2bfbits(fc1w[k * 128 + nn]); }
  if (t < 8192)  { int nn = t >> 7, k = t & 127; F2T[t] = f2bfbits(fc2w[k * 64 + nn]); }
  if (t < 768)   stats[t] = 0.f;
  if (t < N_NODES) deg[t] = 0;
}

// ---------------- CSR build ----------------
__global__ void deg_count(const int* __restrict__ ei, int* __restrict__ deg) {
  int e = blockIdx.x * 256 + threadIdx.x;
  if (e < N_EDGES) atomicAdd(&deg[ei[N_EDGES + e]], 1);
}

__global__ void scanA(const int* __restrict__ deg, int* __restrict__ rowstart,
                      int* __restrict__ bsum) {
  __shared__ int s[256];
  int t = threadIdx.x, i = blockIdx.x * 256 + t;
  int v = (i < N_NODES) ? deg[i] : 0;
  s[t] = v;
  __syncthreads();
#pragma unroll
  for (int off = 1; off < 256; off <<= 1) {
    int u = (t >= off) ? s[t - off] : 0;
    __syncthreads();
    s[t] += u;
    __syncthreads();
  }
  if (i < N_NODES) rowstart[i] = s[t] - v;
  if (t == 0) bsum[blockIdx.x] = s[255];
}

__global__ void scanB(const int* __restrict__ bsum, int* __restrict__ boff) {
  __shared__ int s[512];
  int t = threadIdx.x;
  int v = (t < NBLK) ? bsum[t] : 0;
  s[t] = v;
  __syncthreads();
#pragma unroll
  for (int off = 1; off < 512; off <<= 1) {
    int u = (t >= off) ? s[t - off] : 0;
    __syncthreads();
    s[t] += u;
    __syncthreads();
  }
  if (t < NBLK) boff[t] = s[t] - v;   // exclusive
}

__global__ void scanC(int* __restrict__ rowstart, const int* __restrict__ boff,
                      int* __restrict__ cursor) {
  int i = blockIdx.x * 256 + threadIdx.x;
  if (i < N_NODES) {
    int v = rowstart[i] + boff[i >> 8];
    rowstart[i] = v;
    cursor[i] = v;
  }
  if (i == 0) rowstart[N_NODES] = N_EDGES;
}

__global__ void csr_fill(const int* __restrict__ ei, int* __restrict__ cursor,
                         int* __restrict__ csr_src) {
  int e = blockIdx.x * 256 + threadIdx.x;
  if (e < N_EDGES) {
    int pos = atomicAdd(&cursor[ei[N_EDGES + e]], 1);
    csr_src[pos] = ei[e];
  }
}

// ---------------- gather: agg_bf16[i] = h[i] + sum_{j in N(i)} h[j] ----------------
__global__ __launch_bounds__(256)
void gather_x(const float* __restrict__ x, const int* __restrict__ rowstart,
              const int* __restrict__ csr, unsigned short* __restrict__ aggB) {
  int node = blockIdx.x * 4 + (threadIdx.x >> 6);
  int lane = threadIdx.x & 63;
  int c = lane * 2;
  int rs = rowstart[node], re = rowstart[node + 1];
  fl2 a = *reinterpret_cast<const fl2*>(x + (long)node * DIM_H + c);
  int j = rs;
  for (; j + 1 < re; j += 2) {
    int s0 = csr[j], s1 = csr[j + 1];
    fl2 p = *reinterpret_cast<const fl2*>(x + (long)s0 * DIM_H + c);
    fl2 q = *reinterpret_cast<const fl2*>(x + (long)s1 * DIM_H + c);
    a.x += p.x + q.x; a.y += p.y + q.y;
  }
  if (j < re) {
    int s0 = csr[j];
    fl2 p = *reinterpret_cast<const fl2*>(x + (long)s0 * DIM_H + c);
    a.x += p.x; a.y += p.y;
  }
  unsigned int pk = ((unsigned int)f2bfbits(a.y) << 16) | f2bfbits(a.x);
  *reinterpret_cast<unsigned int*>(aggB + (long)node * DIM_H + c) = pk;
}

// agg_bf16[i] = sum over {i}∪N(i) of (s*z_j + b); s,b computed from BN stats inline
__global__ __launch_bounds__(256)
void gather_z(const unsigned short* __restrict__ Z, const float* __restrict__ stats,
              const float* __restrict__ gamma, const float* __restrict__ beta,
              const int* __restrict__ rowstart, const int* __restrict__ csr,
              unsigned short* __restrict__ aggB) {
  int node = blockIdx.x * 4 + (threadIdx.x >> 6);
  int lane = threadIdx.x & 63;
  int c = lane * 2;
  const float inv_n = 1.0f / (float)N_NODES;
  float m0 = stats[c] * inv_n,      m1 = stats[c + 1] * inv_n;
  float v0 = stats[128 + c] * inv_n - m0 * m0;
  float v1 = stats[128 + c + 1] * inv_n - m1 * m1;
  float sc0 = gamma[c] * rsqrtf(v0 + BN_EPS);
  float sc1 = gamma[c + 1] * rsqrtf(v1 + BN_EPS);
  float bc0 = beta[c] - m0 * sc0;
  float bc1 = beta[c + 1] - m1 * sc1;

  int rs = rowstart[node], re = rowstart[node + 1];
  unsigned int zv = *reinterpret_cast<const unsigned int*>(Z + (long)node * DIM_H + c);
  float a0 = bf2f((unsigned short)zv), a1 = bf2f((unsigned short)(zv >> 16));
  int j = rs;
  for (; j + 1 < re; j += 2) {
    int s0 = csr[j], s1 = csr[j + 1];
    unsigned int p = *reinterpret_cast<const unsigned int*>(Z + (long)s0 * DIM_H + c);
    unsigned int q = *reinterpret_cast<const unsigned int*>(Z + (long)s1 * DIM_H + c);
    a0 += bf2f((unsigned short)p) + bf2f((unsigned short)q);
    a1 += bf2f((unsigned short)(p >> 16)) + bf2f((unsigned short)(q >> 16));
  }
  if (j < re) {
    int s0 = csr[j];
    unsigned int p = *reinterpret_cast<const unsigned int*>(Z + (long)s0 * DIM_H + c);
    a0 += bf2f((unsigned short)p);
    a1 += bf2f((unsigned short)(p >> 16));
  }
  float cnt = (float)(re - rs + 1);
  float o0 = sc0 * a0 + cnt * bc0;
  float o1 = sc1 * a1 + cnt * bc1;
  unsigned int pk = ((unsigned int)f2bfbits(o1) << 16) | f2bfbits(o0);
  *reinterpret_cast<unsigned int*>(aggB + (long)node * DIM_H + c) = pk;
}

// ---------------- fused GIN MLP: barrier-light, weights from L2 ----------------
__global__ __launch_bounds__(256, 4)
void mlp_kernel(const unsigned short* __restrict__ A,
                const unsigned short* __restrict__ W1T, const float* __restrict__ b1,
                const unsigned short* __restrict__ W2T, const float* __restrict__ b2,
                unsigned short* __restrict__ Z, float* __restrict__ stats) {
  __shared__ __align__(16) unsigned short ybuf[128 * WPAD];   // 34816 B
  __shared__ float red[4][2][128];                            //  4096 B

  const int tid = threadIdx.x;
  const int wid = tid >> 6, lane = tid & 63;
  const int lr = lane & 15, lg = lane >> 4;
  const int row0 = blockIdx.x * 128;

  // A fragments straight from bf16 global
  bh8 afrag[2][4];
#pragma unroll
  for (int rt = 0; rt < 2; ++rt) {
    int row = row0 + wid * 32 + rt * 16 + lr;
    bool valid = row < N_NODES;
    const unsigned short* ap = A + (long)row * DIM_H;
#pragma unroll
    for (int kk = 0; kk < 4; ++kk) {
      us8 t = (us8)0;
      if (valid) t = *reinterpret_cast<const us8*>(ap + kk * 32 + 8 * lg);
      afrag[rt][kk] = __builtin_bit_cast(bh8, t);
    }
  }

  // GEMM1 + bias + relu -> ybuf (bf16), B-fragments from global (L2-resident)
#pragma unroll
  for (int n0 = 0; n0 < 8; ++n0) {
    fl4 acc[2] = {{0,0,0,0},{0,0,0,0}};
#pragma unroll
    for (int kk = 0; kk < 4; ++kk) {
      bh8 b = *reinterpret_cast<const bh8*>(&W1T[(n0 * 16 + lr) * 128 + kk * 32 + 8 * lg]);
      acc[0] = __builtin_amdgcn_mfma_f32_16x16x32_bf16(afrag[0][kk], b, acc[0], 0, 0, 0);
      acc[1] = __builtin_amdgcn_mfma_f32_16x16x32_bf16(afrag[1][kk], b, acc[1], 0, 0, 0);
    }
    float bias = b1[n0 * 16 + lr];
#pragma unroll
    for (int rt = 0; rt < 2; ++rt)
#pragma unroll
      for (int r = 0; r < 4; ++r) {
        float v = acc[rt][r] + bias;
        v = v > 0.f ? v : 0.f;
        ybuf[(wid * 32 + rt * 16 + 4 * lg + r) * WPAD + n0 * 16 + lr] = f2bfbits(v);
      }
  }

  wave_lds_fence();          // own-wave rows only: in-wave fence suffices

  // A2 fragments from ybuf
  bh8 a2[2][4];
#pragma unroll
  for (int rt = 0; rt < 2; ++rt)
#pragma unroll
    for (int kk = 0; kk < 4; ++kk)
      a2[rt][kk] = *reinterpret_cast<const bh8*>(
          &ybuf[(wid * 32 + rt * 16 + lr) * WPAD + kk * 32 + 8 * lg]);

  // GEMM2 + bias + relu -> ybuf (z), accumulate BN stats
#pragma unroll
  for (int n0 = 0; n0 < 8; ++n0) {
    fl4 acc[2] = {{0,0,0,0},{0,0,0,0}};
#pragma unroll
    for (int kk = 0; kk < 4; ++kk) {
      bh8 b = *reinterpret_cast<const bh8*>(&W2T[(n0 * 16 + lr) * 128 + kk * 32 + 8 * lg]);
      acc[0] = __builtin_amdgcn_mfma_f32_16x16x32_bf16(a2[0][kk], b, acc[0], 0, 0, 0);
      acc[1] = __builtin_amdgcn_mfma_f32_16x16x32_bf16(a2[1][kk], b, acc[1], 0, 0, 0);
    }
    float bias = b2[n0 * 16 + lr];
    float sp = 0.f, qp = 0.f;
#pragma unroll
    for (int rt = 0; rt < 2; ++rt)
#pragma unroll
      for (int r = 0; r < 4; ++r) {
        int row = row0 + wid * 32 + rt * 16 + 4 * lg + r;
        float v = acc[rt][r] + bias;
        v = v > 0.f ? v : 0.f;
        ybuf[(wid * 32 + rt * 16 + 4 * lg + r) * WPAD + n0 * 16 + lr] = f2bfbits(v);
        if (row < N_NODES) { sp += v; qp += v * v; }
      }
    sp += __shfl_xor(sp, 16); sp += __shfl_xor(sp, 32);
    qp += __shfl_xor(qp, 16); qp += __shfl_xor(qp, 32);
    if (lg == 0) { red[wid][0][n0 * 16 + lr] = sp; red[wid][1][n0 * 16 + lr] = qp; }
  }

  wave_lds_fence();

  // per-wave coalesced z store (own 32 rows)
#pragma unroll
  for (int i = 0; i < 8; ++i) {
    int ch = i * 64 + lane;               // 0..511
    int r  = wid * 32 + (ch >> 4);
    int c8 = (ch & 15) << 3;
    int row = row0 + r;
    if (row < N_NODES)
      *reinterpret_cast<uint4*>(&Z[(long)row * DIM_H + c8]) =
          *reinterpret_cast<const uint4*>(&ybuf[r * WPAD + c8]);
  }

  __syncthreads();           // only cross-wave dependency: stats reduce

  {
    int which = tid >> 7, c = tid & 127;
    float v = red[0][which][c] + red[1][which][c] + red[2][which][c] + red[3][which][c];
    unsafeAtomicAdd(&stats[which * 128 + c], v);
  }
}

// ---------------- head: BN-affine -> fc1 -> relu -> dropout -> fc2 -> log_softmax ----------------
__global__ __launch_bounds__(256, 4)
void head_kernel(const unsigned short* __restrict__ Z, const float* __restrict__ stats,
                 const float* __restrict__ gamma, const float* __restrict__ beta,
                 const unsigned short* __restrict__ F1T, const float* __restrict__ fc1b,
                 const unsigned short* __restrict__ F2T, const float* __restrict__ fc2b,
                 const float* __restrict__ mask, float* __restrict__ out) {
  __shared__ __align__(16) unsigned short ybuf[128 * WPAD];   // 34816 B

  const int tid = threadIdx.x;
  const int wid = tid >> 6, lane = tid & 63;
  const int lr = lane & 15, lg = lane >> 4;
  const int row0 = blockIdx.x * 128;
  const float inv_n = 1.0f / (float)N_NODES;

  // A fragments: affine(z) in bf16; BN scale/shift computed from raw stats
  bh8 afrag[2][4];
#pragma unroll
  for (int kk = 0; kk < 4; ++kk) {
    int k0 = kk * 32 + 8 * lg;
    fl4 s0, s1, bb0, bb1;
#pragma unroll
    for (int j = 0; j < 4; ++j) {
      int c = k0 + j;
      float mean = stats[c] * inv_n;
      float var  = stats[128 + c] * inv_n - mean * mean;
      float sc   = gamma[c] * rsqrtf(var + BN_EPS);
      s0[j] = sc; bb0[j] = beta[c] - mean * sc;
    }
#pragma unroll
    for (int j = 0; j < 4; ++j) {
      int c = k0 + 4 + j;
      float mean = stats[c] * inv_n;
      float var  = stats[128 + c] * inv_n - mean * mean;
      float sc   = gamma[c] * rsqrtf(var + BN_EPS);
      s1[j] = sc; bb1[j] = beta[c] - mean * sc;
    }
#pragma unroll
    for (int rt = 0; rt < 2; ++rt) {
      int row = row0 + wid * 32 + rt * 16 + lr;
      bool valid = row < N_NODES;
      us8 t = (us8)0;
      if (valid) {
        us8 zv = *reinterpret_cast<const us8*>(Z + (long)row * DIM_H + k0);
#pragma unroll
        for (int j = 0; j < 4; ++j) {
          t[j]     = f2bfbits(bf2f(zv[j])     * s0[j] + bb0[j]);
          t[4 + j] = f2bfbits(bf2f(zv[4 + j]) * s1[j] + bb1[j]);
        }
      }
      afrag[rt][kk] = __builtin_bit_cast(bh8, t);
    }
  }

  // GEMM1 + fc1b + relu + dropout -> ybuf, B-fragments from global
#pragma unroll
  for (int n0 = 0; n0 < 8; ++n0) {
    fl4 acc[2] = {{0,0,0,0},{0,0,0,0}};
#pragma unroll
    for (int kk = 0; kk < 4; ++kk) {
      bh8 b = *reinterpret_cast<const bh8*>(&F1T[(n0 * 16 + lr) * 128 + kk * 32 + 8 * lg]);
      acc[0] = __builtin_amdgcn_mfma_f32_16x16x32_bf16(afrag[0][kk], b, acc[0], 0, 0, 0);
      acc[1] = __builtin_amdgcn_mfma_f32_16x16x32_bf16(afrag[1][kk], b, acc[1], 0, 0, 0);
    }
    float bias = fc1b[n0 * 16 + lr];
#pragma unroll
    for (int rt = 0; rt < 2; ++rt)
#pragma unroll
      for (int r = 0; r < 4; ++r) {
        int row = row0 + wid * 32 + rt * 16 + 4 * lg + r;
        float v = acc[rt][r] + bias;
        v = v > 0.f ? v : 0.f;
        float mk = (row < N_NODES) ? mask[(long)row * DIM_H + n0 * 16 + lr] : 0.f;
        ybuf[(wid * 32 + rt * 16 + 4 * lg + r) * WPAD + n0 * 16 + lr] = f2bfbits(v * mk);
      }
  }

  wave_lds_fence();

  bh8 a2[2][4];
#pragma unroll
  for (int rt = 0; rt < 2; ++rt)
#pragma unroll
    for (int kk = 0; kk < 4; ++kk)
      a2[rt][kk] = *reinterpret_cast<const bh8*>(
          &ybuf[(wid * 32 + rt * 16 + lr) * WPAD + kk * 32 + 8 * lg]);

  // GEMM2 (N=64), B-fragments from global
  fl4 acc2[2][4];
#pragma unroll
  for (int n0 = 0; n0 < 4; ++n0) {
    acc2[0][n0] = (fl4){0,0,0,0};
    acc2[1][n0] = (fl4){0,0,0,0};
#pragma unroll
    for (int kk = 0; kk < 4; ++kk) {
      bh8 b = *reinterpret_cast<const bh8*>(&F2T[(n0 * 16 + lr) * 128 + kk * 32 + 8 * lg]);
      acc2[0][n0] = __builtin_amdgcn_mfma_f32_16x16x32_bf16(a2[0][kk], b, acc2[0][n0], 0, 0, 0);
      acc2[1][n0] = __builtin_amdgcn_mfma_f32_16x16x32_bf16(a2[1][kk], b, acc2[1][n0], 0, 0, 0);
    }
    float bias = fc2b[n0 * 16 + lr];
#pragma unroll
    for (int rt = 0; rt < 2; ++rt)
#pragma unroll
      for (int r = 0; r < 4; ++r) acc2[rt][n0][r] += bias;
  }

  // log_softmax over 64 cols + store
#pragma unroll
  for (int rt = 0; rt < 2; ++rt) {
#pragma unroll
    for (int r = 0; r < 4; ++r) {
      float m = fmaxf(fmaxf(acc2[rt][0][r], acc2[rt][1][r]),
                      fmaxf(acc2[rt][2][r], acc2[rt][3][r]));
#pragma unroll
      for (int d = 1; d < 16; d <<= 1) m = fmaxf(m, __shfl_xor(m, d, 16));
      float se = 0.f;
#pragma unroll
      for (int n0 = 0; n0 < 4; ++n0) se += __expf(acc2[rt][n0][r] - m);
#pragma unroll
      for (int d = 1; d < 16; d <<= 1) se += __shfl_xor(se, d, 16);
      float lse = m + __logf(se);
      int row = row0 + wid * 32 + rt * 16 + 4 * lg + r;
      if (row < N_NODES) {
#pragma unroll
        for (int n0 = 0; n0 < 4; ++n0)
          out[(long)row * DIM_OUT + n0 * 16 + lr] = acc2[rt][n0][r] - lse;
      }
    }
  }
}

// ---------------- launcher ----------------
extern "C" void kernel_launch(void* const* d_in, const int* in_sizes, int n_in,
                              void* d_out, int out_size, void* d_ws, size_t ws_size,
                              hipStream_t stream) {
  const float* x      = (const float*)d_in[0];
  const int*   ei     = (const int*)d_in[1];
  const float* cw1    = (const float*)d_in[2];
  const float* cb1    = (const float*)d_in[3];
  const float* cw2    = (const float*)d_in[4];
  const float* cb2    = (const float*)d_in[5];
  const float* gamma  = (const float*)d_in[6];
  const float* beta   = (const float*)d_in[7];
  const float* fc1w   = (const float*)d_in[8];
  const float* fc1b   = (const float*)d_in[9];
  const float* fc2w   = (const float*)d_in[10];
  const float* fc2b   = (const float*)d_in[11];
  const float* mask   = (const float*)d_in[12];
  float* out = (float*)d_out;

  char* ws = (char*)d_ws;
  unsigned short* aggB  = (unsigned short*)ws;                 // 25,600,000 B
  unsigned short* Zb    = (unsigned short*)(ws + 25600000);    // 25,600,000 B
  unsigned short* W1T   = (unsigned short*)(ws + 51200000);    //     98,304 B
  unsigned short* W2T   = (unsigned short*)(ws + 51298304);    //     98,304 B
  unsigned short* F1T   = (unsigned short*)(ws + 51396608);    //     32,768 B
  unsigned short* F2T   = (unsigned short*)(ws + 51429376);    //     16,384 B
  float*          stats = (float*)(ws + 51445760);             //      3,072 B
  int*            rowst = (int*)(ws + 51448832);               //    400,004 B
  int*            cursor= (int*)(ws + 51848836);               //    400,000 B
  int*            csr   = (int*)(ws + 52248836);               //  2,400,000 B
  int*            bsum  = (int*)(ws + 54648836);               //      1,564 B
  int*            boff  = (int*)(ws + 54650400);               //      1,564 B
  if (ws_size < 54651964u) return;

  prep_kernel<<<NBLK, 256, 0, stream>>>(cw1, cw2, fc1w, fc2w, W1T, W2T, F1T, F2T,
                                        stats, cursor);        // cursor doubles as deg

  // CSR build (graph shared by all 3 layers)
  deg_count<<<2344, 256, 0, stream>>>(ei, cursor);
  scanA<<<NBLK, 256, 0, stream>>>(cursor, rowst, bsum);
  scanB<<<1, 512, 0, stream>>>(bsum, boff);
  scanC<<<NBLK, 256, 0, stream>>>(rowst, boff, cursor);
  csr_fill<<<2344, 256, 0, stream>>>(ei, cursor, csr);

  // layer 0 (h = x, fp32)
  gather_x<<<25000, 256, 0, stream>>>(x, rowst, csr, aggB);
  mlp_kernel<<<782, 256, 0, stream>>>(aggB, W1T, cb1, W2T, cb2, Zb, stats);

  // layer 1
  gather_z<<<25000, 256, 0, stream>>>(Zb, stats, gamma, beta, rowst, csr, aggB);
  mlp_kernel<<<782, 256, 0, stream>>>(aggB, W1T + 16384, cb1 + 128, W2T + 16384, cb2 + 128,
                                      Zb, stats + 256);

  // layer 2
  gather_z<<<25000, 256, 0, stream>>>(Zb, stats + 256, gamma + 128, beta + 128,
                                      rowst, csr, aggB);
  mlp_kernel<<<782, 256, 0, stream>>>(aggB, W1T + 32768, cb1 + 256, W2T + 32768, cb2 + 256,
                                      Zb, stats + 512);

  // head
  head_kernel<<<782, 256, 0, stream>>>(Zb, stats + 512, gamma + 256, beta + 256,
                                       F1T, fc1b, F2T, fc2b, mask, out);
}

// Round 5
// 366.855 us; speedup vs baseline: 1.1418x; 1.1418x over previous
//
#include <hip/hip_runtime.h>
#include <stdint.h>

#define N_NODES 100000
#define N_EDGES 600000
#define DIM_H   128
#define DIM_OUT 64
#define WPAD    136      // padded LDS row stride in ushort units (272B)
#define BN_EPS  1e-5f
#define NBLK    391      // ceil(N_NODES/256)

typedef __attribute__((ext_vector_type(8))) __bf16        bh8;
typedef __attribute__((ext_vector_type(4))) float         fl4;
typedef __attribute__((ext_vector_type(8))) unsigned short us8;
typedef __attribute__((ext_vector_type(4))) unsigned short us4;

__device__ __forceinline__ unsigned short f2bfbits(float f) {
  unsigned int u = __builtin_bit_cast(unsigned int, f);
  u += 0x7fffu + ((u >> 16) & 1u);           // RNE
  return (unsigned short)(u >> 16);
}
__device__ __forceinline__ float bf2f(unsigned short b) {
  unsigned int u = ((unsigned int)b) << 16;
  return __builtin_bit_cast(float, u);
}
// in-wave LDS producer->consumer fence (lanes of the same wave only)
__device__ __forceinline__ void wave_lds_fence() {
  asm volatile("s_waitcnt lgkmcnt(0)" ::: "memory");
  __builtin_amdgcn_sched_barrier(0);
}

// ---------------- weight prep (fragment-linear layout) + zero stats/deg ----------------
// fragment layout: offset o = ((n0*4+kk)*64 + lane)*8 + j  maps to  W[k][n],
//   k = kk*32 + (lane>>4)*8 + j,  n = n0*16 + (lane&15)
// so a wave's B-fragment load for (n0,kk) is 64 lanes x 16B fully contiguous.
__global__ void prep_kernel(const float* __restrict__ cw1, const float* __restrict__ cw2,
                            const float* __restrict__ fc1w, const float* __restrict__ fc2w,
                            unsigned short* __restrict__ W1F, unsigned short* __restrict__ W2F,
                            unsigned short* __restrict__ F1F, unsigned short* __restrict__ F2F,
                            float* __restrict__ stats, int* __restrict__ deg) {
  int t = blockIdx.x * 256 + threadIdx.x;
  if (t < 3 * 16384) {
    int l = t >> 14, o = t & 16383;
    int j = o & 7, lane = (o >> 3) & 63, kk = (o >> 9) & 3, n0 = o >> 11;
    int k = kk * 32 + ((lane >> 4) << 3) + j;
    int n = (n0 << 4) + (lane & 15);
    W1F[t] = f2bfbits(cw1[l * 16384 + k * 128 + n]);
    W2F[t] = f2bfbits(cw2[l * 16384 + k * 128 + n]);
  }
  if (t < 16384) {
    int o = t;
    int j = o & 7, lane = (o >> 3) & 63, kk = (o >> 9) & 3, n0 = o >> 11;
    int k = kk * 32 + ((lane >> 4) << 3) + j;
    int n = (n0 << 4) + (lane & 15);
    F1F[t] = f2bfbits(fc1w[k * 128 + n]);
  }
  if (t < 8192) {
    int o = t;
    int j = o & 7, lane = (o >> 3) & 63, kk = (o >> 9) & 3, n0 = o >> 11;
    int k = kk * 32 + ((lane >> 4) << 3) + j;
    int n = (n0 << 4) + (lane & 15);                 // n < 64
    F2F[t] = f2bfbits(fc2w[k * 64 + n]);
  }
  if (t < 768)   stats[t] = 0.f;
  if (t < N_NODES) deg[t] = 0;
}

// ---------------- CSR build ----------------
__global__ void deg_count(const int* __restrict__ ei, int* __restrict__ deg) {
  int e = blockIdx.x * 256 + threadIdx.x;
  if (e < N_EDGES) atomicAdd(&deg[ei[N_EDGES + e]], 1);
}

__global__ void scanA(const int* __restrict__ deg, int* __restrict__ rowstart,
                      int* __restrict__ bsum) {
  __shared__ int s[256];
  int t = threadIdx.x, i = blockIdx.x * 256 + t;
  int v = (i < N_NODES) ? deg[i] : 0;
  s[t] = v;
  __syncthreads();
#pragma unroll
  for (int off = 1; off < 256; off <<= 1) {
    int u = (t >= off) ? s[t - off] : 0;
    __syncthreads();
    s[t] += u;
    __syncthreads();
  }
  if (i < N_NODES) rowstart[i] = s[t] - v;
  if (t == 0) bsum[blockIdx.x] = s[255];
}

__global__ void scanB(const int* __restrict__ bsum, int* __restrict__ boff) {
  __shared__ int s[512];
  int t = threadIdx.x;
  int v = (t < NBLK) ? bsum[t] : 0;
  s[t] = v;
  __syncthreads();
#pragma unroll
  for (int off = 1; off < 512; off <<= 1) {
    int u = (t >= off) ? s[t - off] : 0;
    __syncthreads();
    s[t] += u;
    __syncthreads();
  }
  if (t < NBLK) boff[t] = s[t] - v;   // exclusive
}

__global__ void scanC(int* __restrict__ rowstart, const int* __restrict__ boff,
                      int* __restrict__ cursor) {
  int i = blockIdx.x * 256 + threadIdx.x;
  if (i < N_NODES) {
    int v = rowstart[i] + boff[i >> 8];
    rowstart[i] = v;
    cursor[i] = v;
  }
  if (i == 0) rowstart[N_NODES] = N_EDGES;
}

__global__ void csr_fill(const int* __restrict__ ei, int* __restrict__ cursor,
                         int* __restrict__ csr_src) {
  int e = blockIdx.x * 256 + threadIdx.x;
  if (e < N_EDGES) {
    int pos = atomicAdd(&cursor[ei[N_EDGES + e]], 1);
    csr_src[pos] = ei[e];
  }
}

// ---------------- gather: one wave per node, half-waves cover 2 rows/iter ----------------
__global__ __launch_bounds__(256)
void gather_x(const float* __restrict__ x, const int* __restrict__ rowstart,
              const int* __restrict__ csr, unsigned short* __restrict__ aggB) {
  int node = blockIdx.x * 4 + (threadIdx.x >> 6);
  int lane = threadIdx.x & 63;
  int half = lane >> 5, lc = lane & 31;
  int c = lc * 4;                       // 4 fp32 cols per lane; 32 lanes = full row
  int rs = rowstart[node], re = rowstart[node + 1];
  int cnt = re - rs + 1;                // {self} + neighbors
  fl4 acc = {0.f, 0.f, 0.f, 0.f};
  int i = half;
  for (; i + 2 < cnt; i += 4) {         // 2 items per half per iter (4 rows in flight)
    int idx0 = (i == 0) ? node : csr[rs + i - 1];
    int idx1 = csr[rs + i + 1];
    fl4 v0 = *reinterpret_cast<const fl4*>(x + (long)idx0 * DIM_H + c);
    fl4 v1 = *reinterpret_cast<const fl4*>(x + (long)idx1 * DIM_H + c);
#pragma unroll
    for (int j = 0; j < 4; ++j) acc[j] += v0[j] + v1[j];
  }
  if (i < cnt) {
    int idx0 = (i == 0) ? node : csr[rs + i - 1];
    fl4 v0 = *reinterpret_cast<const fl4*>(x + (long)idx0 * DIM_H + c);
#pragma unroll
    for (int j = 0; j < 4; ++j) acc[j] += v0[j];
  }
#pragma unroll
  for (int j = 0; j < 4; ++j) acc[j] += __shfl_xor(acc[j], 32);
  if (half == 0) {
    us4 pk;
#pragma unroll
    for (int j = 0; j < 4; ++j) pk[j] = f2bfbits(acc[j]);
    *reinterpret_cast<us4*>(aggB + (long)node * DIM_H + c) = pk;
  }
}

// agg = sum over {i}∪N(i) of (s*z_j + b) = s*sum(z_j) + cnt*b ; s,b from BN stats inline
__global__ __launch_bounds__(256)
void gather_z(const unsigned short* __restrict__ Z, const float* __restrict__ stats,
              const float* __restrict__ gamma, const float* __restrict__ beta,
              const int* __restrict__ rowstart, const int* __restrict__ csr,
              unsigned short* __restrict__ aggB) {
  int node = blockIdx.x * 4 + (threadIdx.x >> 6);
  int lane = threadIdx.x & 63;
  int half = lane >> 5, lc = lane & 31;
  int c = lc * 4;                       // 4 bf16 cols per lane; 32 lanes = full row
  const float inv_n = 1.0f / (float)N_NODES;
  fl4 sc, bc;
#pragma unroll
  for (int j = 0; j < 4; ++j) {
    float mean = stats[c + j] * inv_n;
    float var  = stats[128 + c + j] * inv_n - mean * mean;
    float s = gamma[c + j] * rsqrtf(var + BN_EPS);
    sc[j] = s; bc[j] = beta[c + j] - mean * s;
  }
  int rs = rowstart[node], re = rowstart[node + 1];
  int cnt = re - rs + 1;
  fl4 acc = {0.f, 0.f, 0.f, 0.f};
  int i = half;
  for (; i + 2 < cnt; i += 4) {
    int idx0 = (i == 0) ? node : csr[rs + i - 1];
    int idx1 = csr[rs + i + 1];
    us4 z0 = *reinterpret_cast<const us4*>(Z + (long)idx0 * DIM_H + c);
    us4 z1 = *reinterpret_cast<const us4*>(Z + (long)idx1 * DIM_H + c);
#pragma unroll
    for (int j = 0; j < 4; ++j) acc[j] += bf2f(z0[j]) + bf2f(z1[j]);
  }
  if (i < cnt) {
    int idx0 = (i == 0) ? node : csr[rs + i - 1];
    us4 z0 = *reinterpret_cast<const us4*>(Z + (long)idx0 * DIM_H + c);
#pragma unroll
    for (int j = 0; j < 4; ++j) acc[j] += bf2f(z0[j]);
  }
#pragma unroll
  for (int j = 0; j < 4; ++j) acc[j] += __shfl_xor(acc[j], 32);
  if (half == 0) {
    float fc = (float)cnt;
    us4 pk;
#pragma unroll
    for (int j = 0; j < 4; ++j) pk[j] = f2bfbits(sc[j] * acc[j] + fc * bc[j]);
    *reinterpret_cast<us4*>(aggB + (long)node * DIM_H + c) = pk;
  }
}

// ---------------- fused GIN MLP: fragment-linear LDS weights, conflict-free ----------------
__global__ __launch_bounds__(256, 2)
void mlp_kernel(const unsigned short* __restrict__ A,
                const unsigned short* __restrict__ W1F, const float* __restrict__ b1,
                const unsigned short* __restrict__ W2F, const float* __restrict__ b2,
                unsigned short* __restrict__ Z, float* __restrict__ stats) {
  __shared__ __align__(16) unsigned short wbuf[16384];        // 32768 B, fragment-linear
  __shared__ __align__(16) unsigned short ybuf[128 * WPAD];   // 34816 B
  __shared__ float red[4][2][128];                            //  4096 B

  const int tid = threadIdx.x;
  const int wid = tid >> 6, lane = tid & 63;
  const int lr = lane & 15, lg = lane >> 4;
  const int row0 = blockIdx.x * 128;

  // A fragments straight from bf16 global (issue first; longest latency)
  bh8 afrag[2][4];
#pragma unroll
  for (int rt = 0; rt < 2; ++rt) {
    int row = row0 + wid * 32 + rt * 16 + lr;
    bool valid = row < N_NODES;
    const unsigned short* ap = A + (long)row * DIM_H;
#pragma unroll
    for (int kk = 0; kk < 4; ++kk) {
      us8 t = (us8)0;
      if (valid) t = *reinterpret_cast<const us8*>(ap + kk * 32 + 8 * lg);
      afrag[rt][kk] = __builtin_bit_cast(bh8, t);
    }
  }

  // stage W1F (linear copy, fully coalesced both sides)
#pragma unroll
  for (int i = 0; i < 8; ++i) {
    int ch = i * 256 + tid;
    *reinterpret_cast<uint4*>(&wbuf[ch * 8]) = *reinterpret_cast<const uint4*>(&W1F[ch * 8]);
  }
  __syncthreads();

  // GEMM1 + bias + relu -> ybuf (bf16)
#pragma unroll
  for (int n0 = 0; n0 < 8; ++n0) {
    fl4 acc[2] = {{0,0,0,0},{0,0,0,0}};
#pragma unroll
    for (int kk = 0; kk < 4; ++kk) {
      bh8 b = *reinterpret_cast<const bh8*>(&wbuf[((n0 * 4 + kk) << 9) + lane * 8]);
      acc[0] = __builtin_amdgcn_mfma_f32_16x16x32_bf16(afrag[0][kk], b, acc[0], 0, 0, 0);
      acc[1] = __builtin_amdgcn_mfma_f32_16x16x32_bf16(afrag[1][kk], b, acc[1], 0, 0, 0);
    }
    float bias = b1[n0 * 16 + lr];
#pragma unroll
    for (int rt = 0; rt < 2; ++rt)
#pragma unroll
      for (int r = 0; r < 4; ++r) {
        float v = acc[rt][r] + bias;
        v = v > 0.f ? v : 0.f;
        ybuf[(wid * 32 + rt * 16 + 4 * lg + r) * WPAD + n0 * 16 + lr] = f2bfbits(v);
      }
  }

  __syncthreads();           // all waves done reading W1 (and ybuf written)

  // stage W2F over wbuf
#pragma unroll
  for (int i = 0; i < 8; ++i) {
    int ch = i * 256 + tid;
    *reinterpret_cast<uint4*>(&wbuf[ch * 8]) = *reinterpret_cast<const uint4*>(&W2F[ch * 8]);
  }

  // A2 fragments from ybuf (stable since previous barrier)
  bh8 a2[2][4];
#pragma unroll
  for (int rt = 0; rt < 2; ++rt)
#pragma unroll
    for (int kk = 0; kk < 4; ++kk)
      a2[rt][kk] = *reinterpret_cast<const bh8*>(
          &ybuf[(wid * 32 + rt * 16 + lr) * WPAD + kk * 32 + 8 * lg]);

  __syncthreads();           // W2 staged

  // GEMM2 + bias + relu -> ybuf (z), accumulate BN stats
#pragma unroll
  for (int n0 = 0; n0 < 8; ++n0) {
    fl4 acc[2] = {{0,0,0,0},{0,0,0,0}};
#pragma unroll
    for (int kk = 0; kk < 4; ++kk) {
      bh8 b = *reinterpret_cast<const bh8*>(&wbuf[((n0 * 4 + kk) << 9) + lane * 8]);
      acc[0] = __builtin_amdgcn_mfma_f32_16x16x32_bf16(a2[0][kk], b, acc[0], 0, 0, 0);
      acc[1] = __builtin_amdgcn_mfma_f32_16x16x32_bf16(a2[1][kk], b, acc[1], 0, 0, 0);
    }
    float bias = b2[n0 * 16 + lr];
    float sp = 0.f, qp = 0.f;
#pragma unroll
    for (int rt = 0; rt < 2; ++rt)
#pragma unroll
      for (int r = 0; r < 4; ++r) {
        int row = row0 + wid * 32 + rt * 16 + 4 * lg + r;
        float v = acc[rt][r] + bias;
        v = v > 0.f ? v : 0.f;
        ybuf[(wid * 32 + rt * 16 + 4 * lg + r) * WPAD + n0 * 16 + lr] = f2bfbits(v);
        if (row < N_NODES) { sp += v; qp += v * v; }
      }
    sp += __shfl_xor(sp, 16); sp += __shfl_xor(sp, 32);
    qp += __shfl_xor(qp, 16); qp += __shfl_xor(qp, 32);
    if (lg == 0) { red[wid][0][n0 * 16 + lr] = sp; red[wid][1][n0 * 16 + lr] = qp; }
  }

  wave_lds_fence();

  // per-wave coalesced z store (own 32 rows)
#pragma unroll
  for (int i = 0; i < 8; ++i) {
    int ch = i * 64 + lane;               // 0..511
    int r  = wid * 32 + (ch >> 4);
    int c8 = (ch & 15) << 3;
    int row = row0 + r;
    if (row < N_NODES)
      *reinterpret_cast<uint4*>(&Z[(long)row * DIM_H + c8]) =
          *reinterpret_cast<const uint4*>(&ybuf[r * WPAD + c8]);
  }

  __syncthreads();           // cross-wave stats reduce

  {
    int which = tid >> 7, c = tid & 127;
    float v = red[0][which][c] + red[1][which][c] + red[2][which][c] + red[3][which][c];
    unsafeAtomicAdd(&stats[which * 128 + c], v);
  }
}

// ---------------- head: BN-affine -> fc1 -> relu -> dropout -> fc2 -> log_softmax ----------------
// keeps R4 structure (4 blocks/CU, zero block barriers); B-fragments from global,
// now fragment-linear so each wave load is one contiguous 1KB burst
__global__ __launch_bounds__(256, 4)
void head_kernel(const unsigned short* __restrict__ Z, const float* __restrict__ stats,
                 const float* __restrict__ gamma, const float* __restrict__ beta,
                 const unsigned short* __restrict__ F1F, const float* __restrict__ fc1b,
                 const unsigned short* __restrict__ F2F, const float* __restrict__ fc2b,
                 const float* __restrict__ mask, float* __restrict__ out) {
  __shared__ __align__(16) unsigned short ybuf[128 * WPAD];   // 34816 B

  const int tid = threadIdx.x;
  const int wid = tid >> 6, lane = tid & 63;
  const int lr = lane & 15, lg = lane >> 4;
  const int row0 = blockIdx.x * 128;
  const float inv_n = 1.0f / (float)N_NODES;

  // A fragments: affine(z) in bf16; BN scale/shift from raw stats
  bh8 afrag[2][4];
#pragma unroll
  for (int kk = 0; kk < 4; ++kk) {
    int k0 = kk * 32 + 8 * lg;
    fl4 s0, s1, bb0, bb1;
#pragma unroll
    for (int j = 0; j < 4; ++j) {
      int c = k0 + j;
      float mean = stats[c] * inv_n;
      float var  = stats[128 + c] * inv_n - mean * mean;
      float sc   = gamma[c] * rsqrtf(var + BN_EPS);
      s0[j] = sc; bb0[j] = beta[c] - mean * sc;
    }
#pragma unroll
    for (int j = 0; j < 4; ++j) {
      int c = k0 + 4 + j;
      float mean = stats[c] * inv_n;
      float var  = stats[128 + c] * inv_n - mean * mean;
      float sc   = gamma[c] * rsqrtf(var + BN_EPS);
      s1[j] = sc; bb1[j] = beta[c] - mean * sc;
    }
#pragma unroll
    for (int rt = 0; rt < 2; ++rt) {
      int row = row0 + wid * 32 + rt * 16 + lr;
      bool valid = row < N_NODES;
      us8 t = (us8)0;
      if (valid) {
        us8 zv = *reinterpret_cast<const us8*>(Z + (long)row * DIM_H + k0);
#pragma unroll
        for (int j = 0; j < 4; ++j) {
          t[j]     = f2bfbits(bf2f(zv[j])     * s0[j] + bb0[j]);
          t[4 + j] = f2bfbits(bf2f(zv[4 + j]) * s1[j] + bb1[j]);
        }
      }
      afrag[rt][kk] = __builtin_bit_cast(bh8, t);
    }
  }

  // GEMM1 + fc1b + relu + dropout -> ybuf
#pragma unroll
  for (int n0 = 0; n0 < 8; ++n0) {
    fl4 acc[2] = {{0,0,0,0},{0,0,0,0}};
#pragma unroll
    for (int kk = 0; kk < 4; ++kk) {
      bh8 b = *reinterpret_cast<const bh8*>(&F1F[((n0 * 4 + kk) << 9) + lane * 8]);
      acc[0] = __builtin_amdgcn_mfma_f32_16x16x32_bf16(afrag[0][kk], b, acc[0], 0, 0, 0);
      acc[1] = __builtin_amdgcn_mfma_f32_16x16x32_bf16(afrag[1][kk], b, acc[1], 0, 0, 0);
    }
    float bias = fc1b[n0 * 16 + lr];
#pragma unroll
    for (int rt = 0; rt < 2; ++rt)
#pragma unroll
      for (int r = 0; r < 4; ++r) {
        int row = row0 + wid * 32 + rt * 16 + 4 * lg + r;
        float v = acc[rt][r] + bias;
        v = v > 0.f ? v : 0.f;
        float mk = (row < N_NODES) ? mask[(long)row * DIM_H + n0 * 16 + lr] : 0.f;
        ybuf[(wid * 32 + rt * 16 + 4 * lg + r) * WPAD + n0 * 16 + lr] = f2bfbits(v * mk);
      }
  }

  wave_lds_fence();          // own-wave rows only

  bh8 a2[2][4];
#pragma unroll
  for (int rt = 0; rt < 2; ++rt)
#pragma unroll
    for (int kk = 0; kk < 4; ++kk)
      a2[rt][kk] = *reinterpret_cast<const bh8*>(
          &ybuf[(wid * 32 + rt * 16 + lr) * WPAD + kk * 32 + 8 * lg]);

  // GEMM2 (N=64)
  fl4 acc2[2][4];
#pragma unroll
  for (int n0 = 0; n0 < 4; ++n0) {
    acc2[0][n0] = (fl4){0,0,0,0};
    acc2[1][n0] = (fl4){0,0,0,0};
#pragma unroll
    for (int kk = 0; kk < 4; ++kk) {
      bh8 b = *reinterpret_cast<const bh8*>(&F2F[((n0 * 4 + kk) << 9) + lane * 8]);
      acc2[0][n0] = __builtin_amdgcn_mfma_f32_16x16x32_bf16(a2[0][kk], b, acc2[0][n0], 0, 0, 0);
      acc2[1][n0] = __builtin_amdgcn_mfma_f32_16x16x32_bf16(a2[1][kk], b, acc2[1][n0], 0, 0, 0);
    }
    float bias = fc2b[n0 * 16 + lr];
#pragma unroll
    for (int rt = 0; rt < 2; ++rt)
#pragma unroll
      for (int r = 0; r < 4; ++r) acc2[rt][n0][r] += bias;
  }

  // log_softmax over 64 cols + store
#pragma unroll
  for (int rt = 0; rt < 2; ++rt) {
#pragma unroll
    for (int r = 0; r < 4; ++r) {
      float m = fmaxf(fmaxf(acc2[rt][0][r], acc2[rt][1][r]),
                      fmaxf(acc2[rt][2][r], acc2[rt][3][r]));
#pragma unroll
      for (int d = 1; d < 16; d <<= 1) m = fmaxf(m, __shfl_xor(m, d, 16));
      float se = 0.f;
#pragma unroll
      for (int n0 = 0; n0 < 4; ++n0) se += __expf(acc2[rt][n0][r] - m);
#pragma unroll
      for (int d = 1; d < 16; d <<= 1) se += __shfl_xor(se, d, 16);
      float lse = m + __logf(se);
      int row = row0 + wid * 32 + rt * 16 + 4 * lg + r;
      if (row < N_NODES) {
#pragma unroll
        for (int n0 = 0; n0 < 4; ++n0)
          out[(long)row * DIM_OUT + n0 * 16 + lr] = acc2[rt][n0][r] - lse;
      }
    }
  }
}

// ---------------- launcher ----------------
extern "C" void kernel_launch(void* const* d_in, const int* in_sizes, int n_in,
                              void* d_out, int out_size, void* d_ws, size_t ws_size,
                              hipStream_t stream) {
  const float* x      = (const float*)d_in[0];
  const int*   ei     = (const int*)d_in[1];
  const float* cw1    = (const float*)d_in[2];
  const float* cb1    = (const float*)d_in[3];
  const float* cw2    = (const float*)d_in[4];
  const float* cb2    = (const float*)d_in[5];
  const float* gamma  = (const float*)d_in[6];
  const float* beta   = (const float*)d_in[7];
  const float* fc1w   = (const float*)d_in[8];
  const float* fc1b   = (const float*)d_in[9];
  const float* fc2w   = (const float*)d_in[10];
  const float* fc2b   = (const float*)d_in[11];
  const float* mask   = (const float*)d_in[12];
  float* out = (float*)d_out;

  char* ws = (char*)d_ws;
  unsigned short* aggB  = (unsigned short*)ws;                 // 25,600,000 B
  unsigned short* Zb    = (unsigned short*)(ws + 25600000);    // 25,600,000 B
  unsigned short* W1F   = (unsigned short*)(ws + 51200000);    //     98,304 B
  unsigned short* W2F   = (unsigned short*)(ws + 51298304);    //     98,304 B
  unsigned short* F1F   = (unsigned short*)(ws + 51396608);    //     32,768 B
  unsigned short* F2F   = (unsigned short*)(ws + 51429376);    //     16,384 B
  float*          stats = (float*)(ws + 51445760);             //      3,072 B
  int*            rowst = (int*)(ws + 51448832);               //    400,004 B
  int*            cursor= (int*)(ws + 51848836);               //    400,000 B
  int*            csr   = (int*)(ws + 52248836);               //  2,400,000 B
  int*            bsum  = (int*)(ws + 54648836);               //      1,564 B
  int*            boff  = (int*)(ws + 54650400);               //      1,564 B
  if (ws_size < 54651964u) return;

  prep_kernel<<<NBLK, 256, 0, stream>>>(cw1, cw2, fc1w, fc2w, W1F, W2F, F1F, F2F,
                                        stats, cursor);        // cursor doubles as deg

  // CSR build (graph shared by all 3 layers)
  deg_count<<<2344, 256, 0, stream>>>(ei, cursor);
  scanA<<<NBLK, 256, 0, stream>>>(cursor, rowst, bsum);
  scanB<<<1, 512, 0, stream>>>(bsum, boff);
  scanC<<<NBLK, 256, 0, stream>>>(rowst, boff, cursor);
  csr_fill<<<2344, 256, 0, stream>>>(ei, cursor, csr);

  // layer 0 (h = x, fp32)
  gather_x<<<25000, 256, 0, stream>>>(x, rowst, csr, aggB);
  mlp_kernel<<<782, 256, 0, stream>>>(aggB, W1F, cb1, W2F, cb2, Zb, stats);

  // layer 1
  gather_z<<<25000, 256, 0, stream>>>(Zb, stats, gamma, beta, rowst, csr, aggB);
  mlp_kernel<<<782, 256, 0, stream>>>(aggB, W1F + 16384, cb1 + 128, W2F + 16384, cb2 + 128,
                                      Zb, stats + 256);

  // layer 2
  gather_z<<<25000, 256, 0, stream>>>(Zb, stats + 256, gamma + 128, beta + 128,
                                      rowst, csr, aggB);
  mlp_kernel<<<782, 256, 0, stream>>>(aggB, W1F + 32768, cb1 + 256, W2F + 32768, cb2 + 256,
                                      Zb, stats + 512);

  // head
  head_kernel<<<782, 256, 0, stream>>>(Zb, stats + 512, gamma + 256, beta + 256,
                                       F1F, fc1b, F2F, fc2b, mask, out);
}